// Round 5
// baseline (289.619 us; speedup 1.0000x reference)
//
#include <hip/hip_runtime.h>

typedef unsigned short u16;
typedef unsigned int u32;
typedef __attribute__((ext_vector_type(2))) u32 u32x2;
typedef __attribute__((ext_vector_type(4))) u32 u32x4;
typedef __attribute__((ext_vector_type(8))) short bf16x8;
typedef __attribute__((ext_vector_type(4))) float f32x4;

// round-to-nearest-even fp32 -> bf16 (scalar fallback)
__device__ __forceinline__ u16 f2bf(float f) {
  u32 b = __float_as_uint(f);
  b += 0x7fffu + ((b >> 16) & 1u);
  return (u16)(b >> 16);
}

// packed fp32x2 -> bf16x2
__device__ __forceinline__ u32 pk2bf(float a, float b) {
#if __has_builtin(__builtin_amdgcn_cvt_pk_bf16_f32)
  return __builtin_bit_cast(u32, __builtin_amdgcn_cvt_pk_bf16_f32(a, b));
#else
  return (u32)f2bf(a) | ((u32)f2bf(b) << 16);
#endif
}

// 2^x via native v_exp_f32 (NOTE: __exp2f is a reserved glibc symbol)
__device__ __forceinline__ float fexp2(float x) {
#if __has_builtin(__builtin_amdgcn_exp2f)
  return __builtin_amdgcn_exp2f(x);
#else
  return exp2f(x);
#endif
}

// async global->LDS, 16B/lane; LDS dst = wave-uniform base + lane*16
__device__ __forceinline__ void gload_lds16(const u16* g, u16* l) {
  __builtin_amdgcn_global_load_lds((const __attribute__((address_space(1))) void*)g,
                                   (__attribute__((address_space(3))) void*)l, 16, 0, 0);
}

// ---------------- fp32 -> bf16 convert, 8 elems/thread ----------------------
__global__ __launch_bounds__(256) void cvt_f32_bf16(const float* __restrict__ in,
                                                    u16* __restrict__ out) {
  long i = ((long)blockIdx.x * 256 + threadIdx.x) * 8;
  u32 u[8];
#pragma unroll
  for (int j = 0; j < 8; j++) {
    u32 b = __float_as_uint(in[i + j]);
    u[j] = (b + 0x7fffu + ((b >> 16) & 1u)) >> 16;
  }
  u32x4 o;
  o[0] = u[0] | (u[1] << 16);
  o[1] = u[2] | (u[3] << 16);
  o[2] = u[4] | (u[5] << 16);
  o[3] = u[6] | (u[7] << 16);
  *(u32x4*)(out + i) = o;
}

// ---------------- shared GEMM core: C[128x128] = A[128xK] * B[128xK]^T ------
// global_load_lds width=16 into UNPADDED 64-elt rows, XOR-swizzled chunks.
__device__ __forceinline__ void gemm_core_128(const u16* __restrict__ A,
                                              const u16* __restrict__ B, int K,
                                              int m0, int n0, u16* As, u16* Bs,
                                              f32x4 acc[4][4]) {
  int t = threadIdx.x;
  int lane = t & 63, w = t >> 6;
  int quad = lane >> 4, l16 = lane & 15;
  int wm = (w >> 1) * 64, wn = (w & 1) * 64;
  int lr = lane >> 3, lc = lane & 7;
  int cg = lc ^ lr;
  int swz = l16 & 7;
  for (int k0 = 0; k0 < K; k0 += 64) {
#pragma unroll
    for (int i = 0; i < 4; i++) {
      int r0 = i * 32 + w * 8;
      gload_lds16(&A[(long)(m0 + r0 + lr) * K + k0 + cg * 8], &As[r0 * 64]);
      gload_lds16(&B[(long)(n0 + r0 + lr) * K + k0 + cg * 8], &Bs[r0 * 64]);
    }
    __syncthreads();
#pragma unroll
    for (int ks = 0; ks < 2; ks++) {
      bf16x8 a[4], b[4];
#pragma unroll
      for (int tm = 0; tm < 4; tm++)
        a[tm] = *(const bf16x8*)&As[(wm + tm * 16 + l16) * 64 + ((ks * 4 + quad) ^ swz) * 8];
#pragma unroll
      for (int tn = 0; tn < 4; tn++)
        b[tn] = *(const bf16x8*)&Bs[(wn + tn * 16 + l16) * 64 + ((ks * 4 + quad) ^ swz) * 8];
#pragma unroll
      for (int tm = 0; tm < 4; tm++)
#pragma unroll
        for (int tn = 0; tn < 4; tn++)
          acc[tm][tn] = __builtin_amdgcn_mfma_f32_16x16x32_bf16(a[tm], b[tn],
                                                                acc[tm][tn], 0, 0, 0);
    }
    __syncthreads();
  }
}

// ---------------- GEMM1 (C^T orientation): A = W_attn rows (features) -------
// C^T[nf][s]: lane holds 4 consecutive features (quad*4+r) for one seq col.
// K/Q -> b64 stores of 4 consecutive d. V scattered (b,h,d,s). which is
// block-uniform (m0>>10). Q pre-scaled by 0.125*log2e.
#define QSCALE 0.1803368801f
__global__ __launch_bounds__(256) void gemm_qkv(const u16* __restrict__ W,
                                                const u16* __restrict__ X,
                                                const float* __restrict__ bias,
                                                u16* __restrict__ Kg,
                                                u16* __restrict__ Qg,
                                                u16* __restrict__ Vg) {
  __shared__ __align__(16) u16 As[128 * 64];
  __shared__ __align__(16) u16 Bs[128 * 64];
  const int K = 1024;
  // XCD swizzle: xcd = lin&7 -> (mb half, sb quarter); 12x16 region per XCD
  int lin = blockIdx.x;
  int xcd = lin & 7, idx = lin >> 3;
  int mb = (idx % 12) + 12 * (xcd & 1);   // feature block [0,24)
  int sb = (idx / 12) + 16 * (xcd >> 1);  // seq block [0,64)
  int m0 = mb * 128, n0 = sb * 128;
  f32x4 acc[4][4];
#pragma unroll
  for (int i = 0; i < 4; i++)
#pragma unroll
    for (int j = 0; j < 4; j++) acc[i][j] = (f32x4)0.0f;
  gemm_core_128(W, X, K, m0, n0, As, Bs, acc);

  int t = threadIdx.x, lane = t & 63, w = t >> 6;
  int quad = lane >> 4, l16 = lane & 15;
  int wm = (w >> 1) * 64, wn = (w & 1) * 64;
  int which = m0 >> 10;  // block-uniform: 0=K, 1=Q, 2=V
#pragma unroll
  for (int tm = 0; tm < 4; tm++) {
    int nf0 = m0 + wm + tm * 16 + quad * 4;  // feature base (4 consecutive)
    int h = (nf0 >> 6) & 15, d0 = nf0 & 63;
    f32x4 bv = *(const f32x4*)&bias[nf0];
#pragma unroll
    for (int tn = 0; tn < 4; tn++) {
      int s_abs = n0 + wn + tn * 16 + l16;
      int b = s_abs >> 11, s = s_abs & 2047;
      long bh = (long)b * 16 + h;
      f32x4 v;
#pragma unroll
      for (int r = 0; r < 4; r++) v[r] = acc[tm][tn][r] + bv[r];
      if (which == 0) {
        u32x2 pk;
        pk[0] = pk2bf(v[0], v[1]);
        pk[1] = pk2bf(v[2], v[3]);
        *(u32x2*)&Kg[(bh * 2048 + s) * 64 + d0] = pk;
      } else if (which == 1) {
        u32x2 pk;
        pk[0] = pk2bf(v[0] * QSCALE, v[1] * QSCALE);
        pk[1] = pk2bf(v[2] * QSCALE, v[3] * QSCALE);
        *(u32x2*)&Qg[(bh * 2048 + s) * 64 + d0] = pk;
      } else {
#pragma unroll
        for (int r = 0; r < 4; r++)
          Vg[(bh * 64 + d0 + r) * 2048 + s] = f2bf(v[r]);
      }
    }
  }
}

// ---------------- GEMM2 (C^T orientation): out = y @ W_out^T + b_out --------
__global__ __launch_bounds__(256) void gemm_out(const u16* __restrict__ W,
                                                const u16* __restrict__ Y,
                                                const float* __restrict__ bias,
                                                float* __restrict__ out) {
  __shared__ __align__(16) u16 As[128 * 64];
  __shared__ __align__(16) u16 Bs[128 * 64];
  const int K = 1024;
  int lin = blockIdx.x;
  int xcd = lin & 7, idx = lin >> 3;
  int mb = idx & 7;                 // feature block [0,8)
  int sb = (idx >> 3) + 8 * xcd;    // seq block [0,64)
  int m0 = mb * 128, n0 = sb * 128;
  f32x4 acc[4][4];
#pragma unroll
  for (int i = 0; i < 4; i++)
#pragma unroll
    for (int j = 0; j < 4; j++) acc[i][j] = (f32x4)0.0f;
  gemm_core_128(W, Y, K, m0, n0, As, Bs, acc);

  int t = threadIdx.x, lane = t & 63, w = t >> 6;
  int quad = lane >> 4, l16 = lane & 15;
  int wm = (w >> 1) * 64, wn = (w & 1) * 64;
#pragma unroll
  for (int tm = 0; tm < 4; tm++) {
    int nf0 = m0 + wm + tm * 16 + quad * 4;
    f32x4 bv = *(const f32x4*)&bias[nf0];
#pragma unroll
    for (int tn = 0; tn < 4; tn++) {
      int s_abs = n0 + wn + tn * 16 + l16;
      f32x4 o;
#pragma unroll
      for (int r = 0; r < 4; r++) o[r] = acc[tm][tn][r] + bv[r];
      *(f32x4*)&out[(long)s_abs * 1024 + nf0] = o;
    }
  }
}

// ---------------- flash attention: S^T, exp2, dbuf staging, XCD swizzle -----
// 512 blocks; bh's 8 q-chunks share one XCD (lin%8 = bh%8). Wave w owns 64 q.
// Double-buffered K/V: prefetch tile t+1 BEFORE computing tile t; single
// barrier per iter (its vmcnt(0) drain lands after the full compute phase).
__global__ __launch_bounds__(256, 2) void attn_kernel(const u16* __restrict__ Qg,
                                                      const u16* __restrict__ Kg,
                                                      const u16* __restrict__ Vg,
                                                      u16* __restrict__ Y) {
  __shared__ __align__(16) u16 Ks[2][64 * 64];    // [kv][d] swizzled
  __shared__ __align__(16) u16 Vs[2][64 * 64];    // [d][kv] swizzled
  __shared__ __align__(16) u16 Ps[4 * 64 * 64];   // per-wave [q][kv] swizzled
  int t = threadIdx.x, lane = t & 63, w = t >> 6;
  int quad = lane >> 4, l16 = lane & 15;
  // XCD swizzle: lin = (bh%8) + 8*qc + 64*(bh/8)
  int lin = blockIdx.x;
  int bh = (lin & 7) + (lin >> 6) * 8;
  int qc = (lin >> 3) & 7;
  int q0 = qc * 256 + w * 64;
  u16* Pw = Ps + w * 64 * 64;
  int lr = lane >> 3, lc = lane & 7, cg = lc ^ lr;
  int swz = l16 & 7;

  const u16* Kbase = Kg + (long)bh * 2048 * 64;
  const u16* Vbase = Vg + (long)bh * 64 * 2048;

  // Q fragments (MFMA B-operand), loaded once
  bf16x8 qf[4][2];
#pragma unroll
  for (int tq = 0; tq < 4; tq++) {
    const u16* qp = Qg + ((long)bh * 2048 + q0 + tq * 16 + l16) * 64;
    qf[tq][0] = *(const bf16x8*)(qp + quad * 8);
    qf[tq][1] = *(const bf16x8*)(qp + 32 + quad * 8);
  }

  float lsum[4] = {0.0f, 0.0f, 0.0f, 0.0f};
  f32x4 acc[4][4];  // [tn d][tq q]  out^T
#pragma unroll
  for (int tn = 0; tn < 4; tn++)
#pragma unroll
    for (int tq = 0; tq < 4; tq++) acc[tn][tq] = (f32x4)0.0f;

  // stage tile 0
#pragma unroll
  for (int j = 0; j < 2; j++) {
    int r0 = j * 32 + w * 8;
    gload_lds16(&Kbase[(long)(r0 + lr) * 64 + cg * 8], &Ks[0][r0 * 64]);
    gload_lds16(&Vbase[(long)(r0 + lr) * 2048 + cg * 8], &Vs[0][r0 * 64]);
  }
  __syncthreads();

  for (int tile = 0; tile < 32; tile++) {
    const u16* Kc = Ks[tile & 1];
    const u16* Vc = Vs[tile & 1];
    // prefetch next tile into the other buffer (overlaps this tile's compute)
    if (tile + 1 < 32) {
      int kv0 = (tile + 1) * 64;
      u16* Kn = Ks[(tile + 1) & 1];
      u16* Vn = Vs[(tile + 1) & 1];
#pragma unroll
      for (int j = 0; j < 2; j++) {
        int r0 = j * 32 + w * 8;
        gload_lds16(&Kbase[(long)(kv0 + r0 + lr) * 64 + cg * 8], &Kn[r0 * 64]);
        gload_lds16(&Vbase[(long)(r0 + lr) * 2048 + kv0 + cg * 8], &Vn[r0 * 64]);
      }
    }

    // K A-fragments: read once, reuse across 4 q-subtiles
    bf16x8 kf[4][2];
#pragma unroll
    for (int tn = 0; tn < 4; tn++)
#pragma unroll
      for (int ks = 0; ks < 2; ks++)
        kf[tn][ks] = *(const bf16x8*)&Kc[(tn * 16 + l16) * 64 + ((ks * 4 + quad) ^ swz) * 8];

#pragma unroll
    for (int tq = 0; tq < 4; tq++) {
      f32x4 s[4];
#pragma unroll
      for (int tn = 0; tn < 4; tn++) s[tn] = (f32x4)0.0f;
#pragma unroll
      for (int ks = 0; ks < 2; ks++)
#pragma unroll
        for (int tn = 0; tn < 4; tn++)
          s[tn] = __builtin_amdgcn_mfma_f32_16x16x32_bf16(kf[tn][ks], qf[tq][ks],
                                                          s[tn], 0, 0, 0);
      int qrow = tq * 16 + l16;
#pragma unroll
      for (int tn = 0; tn < 4; tn++) {
        float e0 = fexp2(s[tn][0]);
        float e1 = fexp2(s[tn][1]);
        float e2 = fexp2(s[tn][2]);
        float e3 = fexp2(s[tn][3]);
        lsum[tq] += (e0 + e1) + (e2 + e3);
        u32x2 pk;
        pk[0] = pk2bf(e0, e1);
        pk[1] = pk2bf(e2, e3);
        int c2 = ((tn * 2 + (quad >> 1)) ^ swz) * 2 + (quad & 1);
        *(u32x2*)&Pw[qrow * 64 + c2 * 4] = pk;
      }
    }

    // out^T += V^T · P^T
#pragma unroll
    for (int ks = 0; ks < 2; ks++) {
      bf16x8 vf[4];
#pragma unroll
      for (int tn = 0; tn < 4; tn++)
        vf[tn] = *(const bf16x8*)&Vc[(tn * 16 + l16) * 64 + ((ks * 4 + quad) ^ swz) * 8];
#pragma unroll
      for (int tq = 0; tq < 4; tq++) {
        bf16x8 pf = *(const bf16x8*)&Pw[(tq * 16 + l16) * 64 + ((ks * 4 + quad) ^ swz) * 8];
#pragma unroll
        for (int tn = 0; tn < 4; tn++)
          acc[tn][tq] = __builtin_amdgcn_mfma_f32_16x16x32_bf16(vf[tn], pf,
                                                                acc[tn][tq], 0, 0, 0);
      }
    }
    // single barrier: ends reads of current buf AND (via vmcnt drain) completes
    // the prefetch issued at the top of this iteration.
    __syncthreads();
  }

  // cross-quad denominator reduction (q = l16 fixed per lane)
#pragma unroll
  for (int tq = 0; tq < 4; tq++) {
    lsum[tq] += __shfl_xor(lsum[tq], 16, 64);
    lsum[tq] += __shfl_xor(lsum[tq], 32, 64);
  }

  // epilogue: out^T row=d=tn*16+quad*4+r, col=q=tq*16+l16
  int b = bh >> 4, h = bh & 15;
#pragma unroll
  for (int tq = 0; tq < 4; tq++) {
    float inv = 1.0f / lsum[tq];
    long row = (long)b * 2048 + q0 + tq * 16 + l16;
#pragma unroll
    for (int tn = 0; tn < 4; tn++) {
      u32x2 pk;
      pk[0] = pk2bf(acc[tn][tq][0] * inv, acc[tn][tq][1] * inv);
      pk[1] = pk2bf(acc[tn][tq][2] * inv, acc[tn][tq][3] * inv);
      *(u32x2*)&Y[row * 1024 + h * 64 + tn * 16 + quad * 4] = pk;
    }
  }
}

// ---------------- launch ----------------------------------------------------
extern "C" void kernel_launch(void* const* d_in, const int* in_sizes, int n_in,
                              void* d_out, int out_size, void* d_ws, size_t ws_size,
                              hipStream_t stream) {
  const float* x = (const float*)d_in[0];       // (4,2048,1024)
  const float* W_attn = (const float*)d_in[1];  // (3072,1024)
  const float* b_attn = (const float*)d_in[2];  // (3072,)
  const float* W_out = (const float*)d_in[3];   // (1024,1024)
  const float* b_out = (const float*)d_in[4];   // (1024,)
  float* out = (float*)d_out;                   // (4,2048,1024) fp32

  char* ws = (char*)d_ws;
  u16* xb = (u16*)ws;                             // 16 MB
  u16* Wab = (u16*)(ws + 16777216);               // 6 MB
  u16* Wob = (u16*)(ws + 16777216 + 6291456);     // 2 MB
  u16* Kg = (u16*)(ws + 25165824);                // (b,h,s,d) 16 MB
  u16* Qg = Kg + 8388608;                         // (b,h,s,d) pre-scaled 16 MB
  u16* Vg = Qg + 8388608;                         // (b,h,d,s) 16 MB
  u16* Yb = xb;  // alias: x dead after GEMM1

  cvt_f32_bf16<<<4096, 256, 0, stream>>>(x, xb);
  cvt_f32_bf16<<<1536, 256, 0, stream>>>(W_attn, Wab);
  cvt_f32_bf16<<<512, 256, 0, stream>>>(W_out, Wob);

  gemm_qkv<<<1536, 256, 0, stream>>>(Wab, xb, b_attn, Kg, Qg, Vg);
  attn_kernel<<<512, 256, 0, stream>>>(Qg, Kg, Vg, Yb);
  gemm_out<<<512, 256, 0, stream>>>(Wob, Yb, b_out, out);
}